// Round 1
// baseline (465.978 us; speedup 1.0000x reference)
//
#include <hip/hip_runtime.h>
#include <hip/hip_bf16.h>

// Problem constants
#define B_  8
#define S_  2048
#define H_  1024
#define P_  4096
#define K_  2048   // 2*H
#define M_  32768  // B*P

typedef unsigned short u16;
using bf16x8 = __attribute__((ext_vector_type(8))) short;   // 8 bf16 = 4 VGPRs
using f32x4  = __attribute__((ext_vector_type(4))) float;

__device__ inline u16 f2bf(float f) {
  union { float f; unsigned u; } c; c.f = f;
  unsigned u = c.u;
  // round-to-nearest-even bf16
  unsigned r = (u + 0x7fffu + ((u >> 16) & 1u)) >> 16;
  return (u16)r;
}

// ---- prep 1: hidden fp32 -> bf16 ---------------------------------------
__global__ void cvt_hidden_k(const float4* __restrict__ src,
                             ushort4* __restrict__ dst, int n4) {
  int i = blockIdx.x * blockDim.x + threadIdx.x;
  int stride = gridDim.x * blockDim.x;
  for (; i < n4; i += stride) {
    float4 v = src[i];
    ushort4 o;
    o.x = f2bf(v.x); o.y = f2bf(v.y); o.z = f2bf(v.z); o.w = f2bf(v.w);
    dst[i] = o;
  }
}

// ---- prep 2: W1 (K x N fp32, k-major) -> W1T (N x K bf16) ---------------
__global__ void transp_w1_k(const float* __restrict__ w1, u16* __restrict__ w1t) {
  __shared__ float tile[32][33];
  int n0 = blockIdx.x * 32;
  int k0 = blockIdx.y * 32;
  int tx = threadIdx.x;   // 0..31
  int ty = threadIdx.y;   // 0..7
#pragma unroll
  for (int i = 0; i < 32; i += 8)
    tile[ty + i][tx] = w1[(size_t)(k0 + ty + i) * H_ + n0 + tx];
  __syncthreads();
#pragma unroll
  for (int i = 0; i < 32; i += 8)
    w1t[(size_t)(n0 + ty + i) * K_ + k0 + tx] = f2bf(tile[tx][ty + i]);
}

// ---- main fused gather-GEMM + GELU + W2 partial contraction -------------
// grid = 2048 blocks (256 M-tiles x 8 N-tiles), 256 threads (4 waves, 2x2)
// Tile 128x128, BK=64, mfma_f32_16x16x32_bf16, each wave owns a 64x64 quad.
__global__ __launch_bounds__(256) void gemm_k(
    const u16*  __restrict__ hidB,   // bf16 hidden [B][S][H]
    const u16*  __restrict__ w1t,    // bf16 W1^T   [N=1024][K=2048]
    const int*  __restrict__ pairs,  // int32 [B][P][2]
    const float* __restrict__ b1,
    const float2* __restrict__ w2,   // W2 rows as float2
    float*      __restrict__ part)   // [8 nt][2 wc][32768 m][2 o]
{
  __shared__ u16 ldsA[128 * 64];
  __shared__ u16 ldsB[128 * 64];

  int bid = blockIdx.x;
  int nt = bid & 7;
  int mt = bid >> 3;
  int n0 = nt * 128;
  int m0 = mt * 128;
  int bI = m0 >> 12;       // batch (block lies within one b since 128 | 4096)
  int p0 = m0 & 4095;

  int t = threadIdx.x;
  int w = t >> 6;          // wave 0..3
  int l = t & 63;
  int lr = l & 15;
  int lj = l >> 4;
  int wr = w >> 1;         // wave row (M)
  int wc = w & 1;          // wave col (N)

  // preload pair (s0,s1) per staging row (row r = it*32 + w*8 + l/8)
  int2 sv[4];
#pragma unroll
  for (int it = 0; it < 4; ++it) {
    int r = it * 32 + w * 8 + (l >> 3);
    sv[it] = ((const int2*)pairs)[bI * P_ + p0 + r];
  }

  f32x4 acc[4][4];
#pragma unroll
  for (int i = 0; i < 4; ++i)
#pragma unroll
    for (int j = 0; j < 4; ++j)
      acc[i][j] = (f32x4){0.f, 0.f, 0.f, 0.f};

  const u16* hidBase = hidB + ((size_t)bI << 21);  // b * S_*H_

  for (int kt = 0; kt < K_ / 64; ++kt) {
    int k0 = kt * 64;
    int kcol = k0 & 1023;     // column within the selected half-row
    int half = k0 >> 10;      // 0 -> emb1, 1 -> emb2 (BK=64 divides 1024)

    // ---- stage A (gathered hidden rows) and B (W1T rows) into LDS ----
    // linear LDS dest (wave-uniform base + lane*16), XOR-swizzle applied on
    // the GLOBAL source granule (rule: both-sides-or-neither).
#pragma unroll
    for (int it = 0; it < 4; ++it) {
      int r  = it * 32 + w * 8 + (l >> 3);   // tile row 0..127
      int gs = (l & 7) ^ (r & 7);            // pre-swizzled source granule
      int s  = half ? sv[it].y : sv[it].x;
      __builtin_amdgcn_global_load_lds(
          (const __attribute__((address_space(1))) void*)
              (hidBase + (((size_t)s) << 10) + kcol + gs * 8),
          (__attribute__((address_space(3))) void*)&ldsA[(it * 32 + w * 8) * 64],
          16, 0, 0);
      __builtin_amdgcn_global_load_lds(
          (const __attribute__((address_space(1))) void*)
              (w1t + ((size_t)(n0 + r)) * K_ + k0 + gs * 8),
          (__attribute__((address_space(3))) void*)&ldsB[(it * 32 + w * 8) * 64],
          16, 0, 0);
    }
    __syncthreads();

    // ---- compute: 2 k-slices x 16 MFMA ----
#pragma unroll
    for (int ks = 0; ks < 2; ++ks) {
      bf16x8 af[4], bfv[4];
      int gw = ks * 4 + lj;                  // wanted granule (8 bf16 each)
#pragma unroll
      for (int mi = 0; mi < 4; ++mi) {
        int row = wr * 64 + mi * 16 + lr;
        af[mi] = *(const bf16x8*)&ldsA[row * 64 + ((gw ^ (row & 7)) * 8)];
      }
#pragma unroll
      for (int ni = 0; ni < 4; ++ni) {
        int row = wc * 64 + ni * 16 + lr;
        bfv[ni] = *(const bf16x8*)&ldsB[row * 64 + ((gw ^ (row & 7)) * 8)];
      }
#pragma unroll
      for (int mi = 0; mi < 4; ++mi)
#pragma unroll
        for (int ni = 0; ni < 4; ++ni)
          acc[mi][ni] = __builtin_amdgcn_mfma_f32_16x16x32_bf16(
              af[mi], bfv[ni], acc[mi][ni], 0, 0, 0);
    }
    __syncthreads();
  }

  // ---- fused epilogue: bias + exact GELU + W2 contraction ----
  // acc element (mi,ni,j): row = wr*64+mi*16+lj*4+j, col = wc*64+ni*16+lr
  float pt0[16], pt1[16];
#pragma unroll
  for (int i = 0; i < 16; ++i) { pt0[i] = 0.f; pt1[i] = 0.f; }
#pragma unroll
  for (int ni = 0; ni < 4; ++ni) {
    int n = n0 + wc * 64 + ni * 16 + lr;
    float bb = b1[n];
    float2 wv = w2[n];
#pragma unroll
    for (int mi = 0; mi < 4; ++mi)
#pragma unroll
      for (int j = 0; j < 4; ++j) {
        float x = acc[mi][ni][j] + bb;
        float g = 0.5f * x * (1.0f + erff(x * 0.70710678118654752f));
        pt0[mi * 4 + j] += g * wv.x;
        pt1[mi * 4 + j] += g * wv.y;
      }
  }
  // reduce across the 16 lanes sharing the same rows (vary lane&15)
#pragma unroll
  for (int off = 1; off < 16; off <<= 1) {
#pragma unroll
    for (int i = 0; i < 16; ++i) {
      pt0[i] += __shfl_xor(pt0[i], off, 64);
      pt1[i] += __shfl_xor(pt1[i], off, 64);
    }
  }
  if (lr == 0) {
    float2* pOut = (float2*)part;
#pragma unroll
    for (int mi = 0; mi < 4; ++mi)
#pragma unroll
      for (int j = 0; j < 4; ++j) {
        int m = m0 + wr * 64 + mi * 16 + lj * 4 + j;
        pOut[(((nt << 1) + wc) << 15) + m] =
            make_float2(pt0[mi * 4 + j], pt1[mi * 4 + j]);
      }
  }
}

// ---- final reduce over 16 partials + b2 ---------------------------------
__global__ void reduce_k(const float2* __restrict__ part,
                         const float* __restrict__ b2,
                         float2* __restrict__ out) {
  int m = blockIdx.x * blockDim.x + threadIdx.x;
  if (m >= M_) return;
  float a0 = b2[0], a1 = b2[1];
#pragma unroll
  for (int q = 0; q < 16; ++q) {
    float2 v = part[((size_t)q << 15) + m];
    a0 += v.x; a1 += v.y;
  }
  out[m] = make_float2(a0, a1);
}

extern "C" void kernel_launch(void* const* d_in, const int* in_sizes, int n_in,
                              void* d_out, int out_size, void* d_ws, size_t ws_size,
                              hipStream_t stream) {
  const float* hidden = (const float*)d_in[0];
  const int*   pairs  = (const int*)d_in[1];
  const float* W1     = (const float*)d_in[2];
  const float* b1     = (const float*)d_in[3];
  const float* W2     = (const float*)d_in[4];
  const float* b2     = (const float*)d_in[5];
  float* out = (float*)d_out;

  // ws layout: hidden_bf16 (32 MiB) | W1T_bf16 (4 MiB) | partials (4 MiB)
  u16* hidB = (u16*)d_ws;
  u16* w1t  = hidB + (size_t)B_ * S_ * H_;
  float* part = (float*)(w1t + (size_t)H_ * K_);

  int n4 = (B_ * S_ * H_) / 4;
  cvt_hidden_k<<<4096, 256, 0, stream>>>((const float4*)hidden, (ushort4*)hidB, n4);
  transp_w1_k<<<dim3(H_ / 32, K_ / 32), dim3(32, 8), 0, stream>>>(W1, w1t);
  gemm_k<<<(M_ / 128) * (H_ / 128), 256, 0, stream>>>(
      hidB, w1t, pairs, b1, (const float2*)W2, part);
  reduce_k<<<(M_ + 255) / 256, 256, 0, stream>>>(
      (const float2*)part, b2, (float2*)out);
}

// Round 2
// 200.332 us; speedup vs baseline: 2.3260x; 2.3260x over previous
//
#include <hip/hip_runtime.h>
#include <hip/hip_bf16.h>

// Problem constants
#define B_  8
#define S_  2048
#define H_  1024
#define P_  4096
#define K_  2048   // 2*H
#define M_  32768  // B*P

typedef unsigned short u16;
using bf16x8 = __attribute__((ext_vector_type(8))) short;   // 8 bf16 = 4 VGPRs
using f32x4  = __attribute__((ext_vector_type(4))) float;

__device__ inline u16 f2bf(float f) {
  union { float f; unsigned u; } c; c.f = f;
  unsigned u = c.u;
  unsigned r = (u + 0x7fffu + ((u >> 16) & 1u)) >> 16;  // RNE
  return (u16)r;
}

// ---- prep 1: hidden fp32 -> bf16 ---------------------------------------
__global__ void cvt_hidden_k(const float4* __restrict__ src,
                             ushort4* __restrict__ dst, int n4) {
  int i = blockIdx.x * blockDim.x + threadIdx.x;
  int stride = gridDim.x * blockDim.x;
  for (; i < n4; i += stride) {
    float4 v = src[i];
    ushort4 o;
    o.x = f2bf(v.x); o.y = f2bf(v.y); o.z = f2bf(v.z); o.w = f2bf(v.w);
    dst[i] = o;
  }
}

// ---- prep 2: W1 (K x N fp32, k-major) -> W1T (N x K bf16) ---------------
__global__ void transp_w1_k(const float* __restrict__ w1, u16* __restrict__ w1t) {
  __shared__ float tile[32][33];
  int n0 = blockIdx.x * 32;
  int k0 = blockIdx.y * 32;
  int tx = threadIdx.x;   // 0..31
  int ty = threadIdx.y;   // 0..7
#pragma unroll
  for (int i = 0; i < 32; i += 8)
    tile[ty + i][tx] = w1[(size_t)(k0 + ty + i) * H_ + n0 + tx];
  __syncthreads();
#pragma unroll
  for (int i = 0; i < 32; i += 8)
    w1t[(size_t)(n0 + ty + i) * K_ + k0 + tx] = f2bf(tile[tx][ty + i]);
}

// ---- main fused gather-GEMM + GELU + W2 partial contraction -------------
// 256x256 tile, BK=64, 8 waves (2M x 4N), double-buffered LDS + prefetch.
// grid = 512 blocks (128 M-tiles x 4 N-tiles), XCD-swizzled so each XCD
// works on exactly one batch (gather working set = 4MB = one L2).
__global__ __launch_bounds__(512, 2) void gemm_k(
    const u16*  __restrict__ hidB,   // bf16 hidden [B][S][H]
    const u16*  __restrict__ w1t,    // bf16 W1^T   [N=1024][K=2048]
    const int*  __restrict__ pairs,  // int32 [B][P][2]
    const float* __restrict__ b1,
    const float2* __restrict__ w2,   // W2 rows as float2
    float*      __restrict__ part)   // [16 q][32768 m] float2
{
  __shared__ u16 ldsA[2][256 * 64];   // 32 KB x2
  __shared__ u16 ldsB[2][256 * 64];   // 32 KB x2

  // XCD-aware bijective swizzle (512 % 8 == 0)
  int orig = blockIdx.x;
  int bid = (orig & 7) * (512 >> 3) + (orig >> 3);
  int nt = bid & 3;
  int mt = bid >> 2;
  int n0 = nt * 256;
  int m0 = mt * 256;
  int bI = m0 >> 12;       // batch index (256 | 4096)
  int pp = m0 & 4095;

  int t = threadIdx.x;
  int w = t >> 6;          // wave 0..7
  int l = t & 63;
  int lr = l & 15;
  int lj = l >> 4;
  int wr = w >> 2;         // wave row (M): 0..1 -> 128 rows each
  int wn = w & 3;          // wave col (N): 0..3 -> 64 cols each

  // pair indices per staging row (row r = it*64 + w*8 + l/8)
  int2 sv[4];
#pragma unroll
  for (int it = 0; it < 4; ++it) {
    int r = it * 64 + w * 8 + (l >> 3);
    sv[it] = ((const int2*)pairs)[bI * P_ + pp + r];
  }

  const u16* hidBase = hidB + ((size_t)bI << 21);  // b * S_*H_

  f32x4 acc[8][4];
#pragma unroll
  for (int i = 0; i < 8; ++i)
#pragma unroll
    for (int j = 0; j < 4; ++j)
      acc[i][j] = (f32x4){0.f, 0.f, 0.f, 0.f};

  // ---- staging: linear LDS dest, XOR-swizzle folded into global source ----
  auto STAGE = [&](int buf, int kt) {
    int k0 = kt * 64;
    int kcol = k0 & 1023;     // column within selected half-row
    int half = k0 >> 10;      // 0 -> emb1, 1 -> emb2
#pragma unroll
    for (int it = 0; it < 4; ++it) {
      int r  = it * 64 + w * 8 + (l >> 3);   // tile row 0..255
      int gs = (l & 7) ^ (r & 7);            // pre-swizzled source granule
      int s  = half ? sv[it].y : sv[it].x;
      __builtin_amdgcn_global_load_lds(
          (const __attribute__((address_space(1))) void*)
              (hidBase + (((size_t)s) << 10) + kcol + gs * 8),
          (__attribute__((address_space(3))) void*)&ldsA[buf][(it * 64 + w * 8) * 64],
          16, 0, 0);
      __builtin_amdgcn_global_load_lds(
          (const __attribute__((address_space(1))) void*)
              (w1t + ((size_t)(n0 + r)) * K_ + k0 + gs * 8),
          (__attribute__((address_space(3))) void*)&ldsB[buf][(it * 64 + w * 8) * 64],
          16, 0, 0);
    }
  };

  STAGE(0, 0);
  __syncthreads();           // vmcnt(0) drain + barrier

  int cur = 0;
  for (int kt = 0; kt < K_ / 64; ++kt) {
    if (kt < K_ / 64 - 1) STAGE(cur ^ 1, kt + 1);   // prefetch next tile

    // ---- compute current tile: 2 k-slices x 32 MFMA ----
#pragma unroll
    for (int ks = 0; ks < 2; ++ks) {
      bf16x8 af[8], bv[4];
      int gw = ks * 4 + lj;                  // wanted granule (8 bf16)
#pragma unroll
      for (int mi = 0; mi < 8; ++mi) {
        int row = wr * 128 + mi * 16 + lr;
        af[mi] = *(const bf16x8*)&ldsA[cur][row * 64 + ((gw ^ (row & 7)) * 8)];
      }
#pragma unroll
      for (int ni = 0; ni < 4; ++ni) {
        int row = wn * 64 + ni * 16 + lr;
        bv[ni] = *(const bf16x8*)&ldsB[cur][row * 64 + ((gw ^ (row & 7)) * 8)];
      }
#pragma unroll
      for (int mi = 0; mi < 8; ++mi)
#pragma unroll
        for (int ni = 0; ni < 4; ++ni)
          acc[mi][ni] = __builtin_amdgcn_mfma_f32_16x16x32_bf16(
              af[mi], bv[ni], acc[mi][ni], 0, 0, 0);
    }
    __syncthreads();         // drains prefetch (vmcnt 0) + lgkm + barrier
    cur ^= 1;
  }

  // ---- fused epilogue: bias + exact GELU + W2 contraction ----
  // acc element (mi,ni,j): row = wr*128+mi*16+lj*4+j, col = wn*64+ni*16+lr
  int q = nt * 4 + wn;
  float2* pOut = (float2*)part;
#pragma unroll
  for (int mi = 0; mi < 8; ++mi) {
    float s0[4] = {0.f, 0.f, 0.f, 0.f};
    float s1[4] = {0.f, 0.f, 0.f, 0.f};
#pragma unroll
    for (int ni = 0; ni < 4; ++ni) {
      int n = n0 + wn * 64 + ni * 16 + lr;
      float bb = b1[n];
      float2 wv = w2[n];
#pragma unroll
      for (int j = 0; j < 4; ++j) {
        float x = acc[mi][ni][j] + bb;
        float g = 0.5f * x * (1.0f + erff(x * 0.70710678118654752f));
        s0[j] += g * wv.x;
        s1[j] += g * wv.y;
      }
    }
#pragma unroll
    for (int off = 1; off < 16; off <<= 1) {
#pragma unroll
      for (int j = 0; j < 4; ++j) {
        s0[j] += __shfl_xor(s0[j], off, 64);
        s1[j] += __shfl_xor(s1[j], off, 64);
      }
    }
    if (lr == 0) {
#pragma unroll
      for (int j = 0; j < 4; ++j) {
        int m = m0 + wr * 128 + mi * 16 + lj * 4 + j;
        pOut[((size_t)q << 15) + m] = make_float2(s0[j], s1[j]);
      }
    }
  }
}

// ---- final reduce over 16 partials + b2 ---------------------------------
__global__ void reduce_k(const float2* __restrict__ part,
                         const float* __restrict__ b2,
                         float2* __restrict__ out) {
  int m = blockIdx.x * blockDim.x + threadIdx.x;
  if (m >= M_) return;
  float a0 = b2[0], a1 = b2[1];
#pragma unroll
  for (int q = 0; q < 16; ++q) {
    float2 v = part[((size_t)q << 15) + m];
    a0 += v.x; a1 += v.y;
  }
  out[m] = make_float2(a0, a1);
}

extern "C" void kernel_launch(void* const* d_in, const int* in_sizes, int n_in,
                              void* d_out, int out_size, void* d_ws, size_t ws_size,
                              hipStream_t stream) {
  const float* hidden = (const float*)d_in[0];
  const int*   pairs  = (const int*)d_in[1];
  const float* W1     = (const float*)d_in[2];
  const float* b1     = (const float*)d_in[3];
  const float* W2     = (const float*)d_in[4];
  const float* b2     = (const float*)d_in[5];
  float* out = (float*)d_out;

  // ws layout: hidden_bf16 (32 MiB) | W1T_bf16 (4 MiB) | partials (4 MiB)
  u16* hidB = (u16*)d_ws;
  u16* w1t  = hidB + (size_t)B_ * S_ * H_;
  float* part = (float*)(w1t + (size_t)H_ * K_);

  int n4 = (B_ * S_ * H_) / 4;
  cvt_hidden_k<<<4096, 256, 0, stream>>>((const float4*)hidden, (ushort4*)hidB, n4);
  transp_w1_k<<<dim3(H_ / 32, K_ / 32), dim3(32, 8), 0, stream>>>(W1, w1t);
  gemm_k<<<(M_ / 256) * (H_ / 256), 512, 0, stream>>>(
      hidB, w1t, pairs, b1, (const float2*)W2, part);
  reduce_k<<<(M_ + 255) / 256, 256, 0, stream>>>(
      (const float2*)part, b2, (float2*)out);
}

// Round 3
// 189.243 us; speedup vs baseline: 2.4623x; 1.0586x over previous
//
#include <hip/hip_runtime.h>
#include <hip/hip_bf16.h>

// Problem constants
#define B_  8
#define S_  2048
#define H_  1024
#define P_  4096
#define K_  2048   // 2*H
#define M_  32768  // B*P
#define NKT 64     // K_ / 32 K-tiles

typedef unsigned short u16;
using bf16x8 = __attribute__((ext_vector_type(8))) short;   // 8 bf16 = 4 VGPRs
using f32x4  = __attribute__((ext_vector_type(4))) float;

#define AS1 __attribute__((address_space(1)))
#define AS3 __attribute__((address_space(3)))

__device__ inline u16 f2bf(float f) {
  union { float f; unsigned u; } c; c.f = f;
  unsigned u = c.u;
  unsigned r = (u + 0x7fffu + ((u >> 16) & 1u)) >> 16;  // RNE
  return (u16)r;
}

// ---- prep 1: hidden fp32 -> bf16 ---------------------------------------
__global__ void cvt_hidden_k(const float4* __restrict__ src,
                             ushort4* __restrict__ dst, int n4) {
  int i = blockIdx.x * blockDim.x + threadIdx.x;
  int stride = gridDim.x * blockDim.x;
  for (; i < n4; i += stride) {
    float4 v = src[i];
    ushort4 o;
    o.x = f2bf(v.x); o.y = f2bf(v.y); o.z = f2bf(v.z); o.w = f2bf(v.w);
    dst[i] = o;
  }
}

// ---- prep 2: W1 (K x N fp32, k-major) -> W1T (N x K bf16) ---------------
__global__ void transp_w1_k(const float* __restrict__ w1, u16* __restrict__ w1t) {
  __shared__ float tile[32][33];
  int n0 = blockIdx.x * 32;
  int k0 = blockIdx.y * 32;
  int tx = threadIdx.x;   // 0..31
  int ty = threadIdx.y;   // 0..7
#pragma unroll
  for (int i = 0; i < 32; i += 8)
    tile[ty + i][tx] = w1[(size_t)(k0 + ty + i) * H_ + n0 + tx];
  __syncthreads();
#pragma unroll
  for (int i = 0; i < 32; i += 8)
    w1t[(size_t)(n0 + ty + i) * K_ + k0 + tx] = f2bf(tile[tx][ty + i]);
}

// ---- main fused gather-GEMM + GELU + W2 partial contraction -------------
// 256x256 tile, BK=32, 8 waves (2M x 4N), 4-buffer LDS rotation with
// counted vmcnt (T3+T4): stage tile kt+3 each phase, wait vmcnt(8) so the
// awaited loads were issued 2 phases (~600 cyc) earlier. grid = 512 blocks,
// XCD-swizzled so each XCD works on one batch (gather set = 4MB = one L2).
__global__ __launch_bounds__(512, 2) void gemm_k(
    const u16*  __restrict__ hidB,   // bf16 hidden [B][S][H]
    const u16*  __restrict__ w1t,    // bf16 W1^T   [N=1024][K=2048]
    const int*  __restrict__ pairs,  // int32 [B][P][2]
    const float* __restrict__ b1,
    const float2* __restrict__ w2,   // W2 rows as float2
    float*      __restrict__ part)   // [16 q][32768 m] float2
{
  __shared__ u16 ldsA[4][256 * 32];   // 16 KB x4
  __shared__ u16 ldsB[4][256 * 32];   // 16 KB x4

  // XCD-aware bijective swizzle (512 % 8 == 0)
  int orig = blockIdx.x;
  int bid = (orig & 7) * (512 >> 3) + (orig >> 3);
  int nt = bid & 3;
  int mt = bid >> 2;
  int n0 = nt * 256;
  int m0 = mt * 256;
  int bI = m0 >> 12;       // batch index (256 | 4096)
  int pp = m0 & 4095;

  int t = threadIdx.x;
  int w = t >> 6;          // wave 0..7
  int l = t & 63;
  int lr = l & 15;
  int lj = l >> 4;
  int wr = w >> 2;         // wave row (M): 0..1 -> 128 rows each
  int wn = w & 3;          // wave col (N): 0..3 -> 64 cols each

  // staging rows owned by this thread (2 rows, one per 8KB load group)
  int r0 = w * 16 + (l >> 2);        // 0..127
  int r1 = 128 + r0;                 // 128..255
  int g0 = (l & 3) ^ (r0 & 3);       // swizzled source granule (r1&3 == r0&3)

  int2 sv0 = ((const int2*)pairs)[bI * P_ + pp + r0];
  int2 sv1 = ((const int2*)pairs)[bI * P_ + pp + r1];

  const u16* hidBase = hidB + ((size_t)bI << 21);  // b * S_*H_

  f32x4 acc[8][4];
#pragma unroll
  for (int i = 0; i < 8; ++i)
#pragma unroll
    for (int j = 0; j < 4; ++j)
      acc[i][j] = (f32x4){0.f, 0.f, 0.f, 0.f};

  // stage K-tile kt into buffer buf: 4 x global_load_lds (A r0, A r1, B r0, B r1)
  auto STAGE = [&](int buf, int kt) {
    int k0 = kt * 32;
    int kcol = k0 & 1023;       // column within selected half-row
    int half = k0 >> 10;        // 0 -> emb1, 1 -> emb2
    int sA0 = half ? sv0.y : sv0.x;
    int sA1 = half ? sv1.y : sv1.x;
    __builtin_amdgcn_global_load_lds(
        (const AS1 void*)(hidBase + (((size_t)sA0) << 10) + kcol + g0 * 8),
        (AS3 void*)&ldsA[buf][w * 512 + l * 8], 16, 0, 0);
    __builtin_amdgcn_global_load_lds(
        (const AS1 void*)(hidBase + (((size_t)sA1) << 10) + kcol + g0 * 8),
        (AS3 void*)&ldsA[buf][4096 + w * 512 + l * 8], 16, 0, 0);
    __builtin_amdgcn_global_load_lds(
        (const AS1 void*)(w1t + (size_t)(n0 + r0) * K_ + k0 + g0 * 8),
        (AS3 void*)&ldsB[buf][w * 512 + l * 8], 16, 0, 0);
    __builtin_amdgcn_global_load_lds(
        (const AS1 void*)(w1t + (size_t)(n0 + r1) * K_ + k0 + g0 * 8),
        (AS3 void*)&ldsB[buf][4096 + w * 512 + l * 8], 16, 0, 0);
  };

// one pipeline phase: ds_read frags(kt) | stage(kt+3) | counted wait |
// barrier | MFMA | barrier
#define PHASE(KT, DOSTAGE, WAITOP)                                            \
  {                                                                           \
    const int buf_ = (KT) & 3;                                                \
    bf16x8 af[8], bv[4];                                                      \
    _Pragma("unroll")                                                         \
    for (int mi = 0; mi < 8; ++mi) {                                          \
      int row = wr * 128 + mi * 16 + lr;                                      \
      af[mi] = *(const bf16x8*)&ldsA[buf_][row * 32 + ((lj ^ (row & 3)) * 8)];\
    }                                                                         \
    _Pragma("unroll")                                                         \
    for (int ni = 0; ni < 4; ++ni) {                                          \
      int row = wn * 64 + ni * 16 + lr;                                       \
      bv[ni] = *(const bf16x8*)&ldsB[buf_][row * 32 + ((lj ^ (row & 3)) * 8)];\
    }                                                                         \
    if (DOSTAGE) STAGE((KT + 3) & 3, (KT) + 3);                               \
    WAITOP;                                                                   \
    __builtin_amdgcn_s_barrier();                                             \
    __builtin_amdgcn_s_setprio(1);                                            \
    _Pragma("unroll")                                                         \
    for (int mi = 0; mi < 8; ++mi)                                            \
      _Pragma("unroll")                                                       \
      for (int ni = 0; ni < 4; ++ni)                                          \
        acc[mi][ni] = __builtin_amdgcn_mfma_f32_16x16x32_bf16(                \
            af[mi], bv[ni], acc[mi][ni], 0, 0, 0);                            \
    __builtin_amdgcn_s_setprio(0);                                            \
    __builtin_amdgcn_s_barrier();                                             \
    asm volatile("" ::: "memory");                                            \
  }

  // prologue: 3 tiles in flight, wait only for tile 0
  STAGE(0, 0); STAGE(1, 1); STAGE(2, 2);
  asm volatile("s_waitcnt vmcnt(8)" ::: "memory");
  __builtin_amdgcn_s_barrier();

  for (int kt = 0; kt < NKT - 3; ++kt)
    PHASE(kt, true, asm volatile("s_waitcnt vmcnt(8)" ::: "memory"));
  PHASE(NKT - 3, false, asm volatile("s_waitcnt vmcnt(4)" ::: "memory"));
  PHASE(NKT - 2, false, asm volatile("s_waitcnt vmcnt(0)" ::: "memory"));
  PHASE(NKT - 1, false, );
#undef PHASE

  // ---- fused epilogue: bias + exact GELU + W2 contraction ----
  // acc element (mi,ni,j): row = wr*128+mi*16+lj*4+j, col = wn*64+ni*16+lr
  int q = nt * 4 + wn;
  float2* pOut = (float2*)part;
#pragma unroll
  for (int mi = 0; mi < 8; ++mi) {
    float s0[4] = {0.f, 0.f, 0.f, 0.f};
    float s1[4] = {0.f, 0.f, 0.f, 0.f};
#pragma unroll
    for (int ni = 0; ni < 4; ++ni) {
      int n = n0 + wn * 64 + ni * 16 + lr;
      float bb = b1[n];
      float2 wv = w2[n];
#pragma unroll
      for (int j = 0; j < 4; ++j) {
        float x = acc[mi][ni][j] + bb;
        float g = 0.5f * x * (1.0f + erff(x * 0.70710678118654752f));
        s0[j] += g * wv.x;
        s1[j] += g * wv.y;
      }
    }
#pragma unroll
    for (int off = 1; off < 16; off <<= 1) {
#pragma unroll
      for (int j = 0; j < 4; ++j) {
        s0[j] += __shfl_xor(s0[j], off, 64);
        s1[j] += __shfl_xor(s1[j], off, 64);
      }
    }
    if (lr == 0) {
#pragma unroll
      for (int j = 0; j < 4; ++j) {
        int m = m0 + wr * 128 + mi * 16 + lj * 4 + j;
        pOut[((size_t)q << 15) + m] = make_float2(s0[j], s1[j]);
      }
    }
  }
}

// ---- final reduce over 16 partials + b2 ---------------------------------
__global__ void reduce_k(const float2* __restrict__ part,
                         const float* __restrict__ b2,
                         float2* __restrict__ out) {
  int m = blockIdx.x * blockDim.x + threadIdx.x;
  if (m >= M_) return;
  float a0 = b2[0], a1 = b2[1];
#pragma unroll
  for (int q = 0; q < 16; ++q) {
    float2 v = part[((size_t)q << 15) + m];
    a0 += v.x; a1 += v.y;
  }
  out[m] = make_float2(a0, a1);
}

extern "C" void kernel_launch(void* const* d_in, const int* in_sizes, int n_in,
                              void* d_out, int out_size, void* d_ws, size_t ws_size,
                              hipStream_t stream) {
  const float* hidden = (const float*)d_in[0];
  const int*   pairs  = (const int*)d_in[1];
  const float* W1     = (const float*)d_in[2];
  const float* b1     = (const float*)d_in[3];
  const float* W2     = (const float*)d_in[4];
  const float* b2     = (const float*)d_in[5];
  float* out = (float*)d_out;

  // ws layout: hidden_bf16 (32 MiB) | W1T_bf16 (4 MiB) | partials (4 MiB)
  u16* hidB = (u16*)d_ws;
  u16* w1t  = hidB + (size_t)B_ * S_ * H_;
  float* part = (float*)(w1t + (size_t)H_ * K_);

  int n4 = (B_ * S_ * H_) / 4;
  cvt_hidden_k<<<4096, 256, 0, stream>>>((const float4*)hidden, (ushort4*)hidB, n4);
  transp_w1_k<<<dim3(H_ / 32, K_ / 32), dim3(32, 8), 0, stream>>>(W1, w1t);
  gemm_k<<<(M_ / 256) * (H_ / 256), 512, 0, stream>>>(
      hidB, w1t, pairs, b1, (const float2*)W2, part);
  reduce_k<<<(M_ + 255) / 256, 256, 0, stream>>>(
      (const float2*)part, b2, (float2*)out);
}

// Round 4
// 173.296 us; speedup vs baseline: 2.6889x; 1.0920x over previous
//
#include <hip/hip_runtime.h>
#include <hip/hip_bf16.h>

// Problem constants
#define B_  8
#define S_  2048
#define H_  1024
#define P_  4096
#define K_  2048   // 2*H
#define M_  32768  // B*P

typedef unsigned short u16;
using bf16x8 = __attribute__((ext_vector_type(8))) short;   // 8 bf16 = 4 VGPRs
using f32x4  = __attribute__((ext_vector_type(4))) float;

#define AS1 __attribute__((address_space(1)))
#define AS3 __attribute__((address_space(3)))

__device__ inline u16 f2bf(float f) {
  union { float f; unsigned u; } c; c.f = f;
  unsigned u = c.u;
  unsigned r = (u + 0x7fffu + ((u >> 16) & 1u)) >> 16;  // RNE
  return (u16)r;
}

// ---- prep 1: hidden fp32 -> bf16 ---------------------------------------
__global__ void cvt_hidden_k(const float4* __restrict__ src,
                             ushort4* __restrict__ dst, int n4) {
  int i = blockIdx.x * blockDim.x + threadIdx.x;
  int stride = gridDim.x * blockDim.x;
  for (; i < n4; i += stride) {
    float4 v = src[i];
    ushort4 o;
    o.x = f2bf(v.x); o.y = f2bf(v.y); o.z = f2bf(v.z); o.w = f2bf(v.w);
    dst[i] = o;
  }
}

// ---- prep 2: W1 (K x N fp32, k-major) -> W1T (N x K bf16) ---------------
__global__ void transp_w1_k(const float* __restrict__ w1, u16* __restrict__ w1t) {
  __shared__ float tile[32][33];
  int n0 = blockIdx.x * 32;
  int k0 = blockIdx.y * 32;
  int tx = threadIdx.x;   // 0..31
  int ty = threadIdx.y;   // 0..7
#pragma unroll
  for (int i = 0; i < 32; i += 8)
    tile[ty + i][tx] = w1[(size_t)(k0 + ty + i) * H_ + n0 + tx];
  __syncthreads();
#pragma unroll
  for (int i = 0; i < 32; i += 8)
    w1t[(size_t)(n0 + ty + i) * K_ + k0 + tx] = f2bf(tile[tx][ty + i]);
}

// ---- main fused gather-GEMM + GELU + W2 partial contraction -------------
// m201-style 8-phase schedule: 256x256 tile, BK=64 as 2 k-slices of 32,
// 8 waves (2M x 4N), 8 x 16KB LDS regions in a ring staged 6 phases ahead,
// vmcnt(6) at even phases (never 0 in main loop), 16-MFMA clusters with
// setprio. Region (slot=tile&1, ks, A/B). 512 blocks, XCD-swizzled so each
// XCD gathers from exactly one batch (4MB = one L2).
__global__ __launch_bounds__(512, 2) void gemm_k(
    const u16*  __restrict__ hidB,   // bf16 hidden [B][S][H]
    const u16*  __restrict__ w1t,    // bf16 W1^T   [N=1024][K=2048]
    const int*  __restrict__ pairs,  // int32 [B][P][2]
    const float* __restrict__ b1,
    const float2* __restrict__ w2,   // W2 rows as float2
    float*      __restrict__ part)   // [16 q][32768 m] float2
{
  __shared__ u16 lds[65536];   // 8 regions x 16KB = 128 KB

#define REG(SLOT, KS, AB) ((((SLOT)*2 + (KS))*2 + (AB)) * 8192)

  // XCD-aware bijective swizzle (512 % 8 == 0)
  int orig = blockIdx.x;
  int bid = (orig & 7) * 64 + (orig >> 3);
  int nt = bid & 3;
  int mt = bid >> 2;
  int n0 = nt * 256;
  int m0 = mt * 256;
  int bI = m0 >> 12;       // batch index (256 | 4096)
  int pp = m0 & 4095;

  int t = threadIdx.x;
  int w = t >> 6;          // wave 0..7
  int l = t & 63;
  int lr = l & 15;
  int lj = l >> 4;
  int wr = w >> 2;         // wave row (M): 0..1 -> 128 rows each
  int wn = w & 3;          // wave col (N): 0..3 -> 64 cols each

  // LDS read slot (16B granule within 64B row), lane-constant:
  // slot = lj ^ ((row>>1)&3) and (row>>1)&3 == (l>>1)&3 for all our rows
  int slot8 = (lj ^ ((l >> 1) & 3)) * 8;   // u16 offset
  // staging source granule (write side of the same involution)
  int gsrc = (l & 3) ^ ((l >> 3) & 3);

  // staging rows owned by this thread (2 rows per region, 2 gloads)
  int r0 = w * 16 + (l >> 2);        // 0..127
  int r1 = 128 + r0;                 // 128..255

  int2 sv0 = ((const int2*)pairs)[bI * P_ + pp + r0];
  int2 sv1 = ((const int2*)pairs)[bI * P_ + pp + r1];

  const u16* hidBase = hidB + ((size_t)bI << 21);  // b * S_*H_

  f32x4 acc[8][4];
#pragma unroll
  for (int i = 0; i < 8; ++i)
#pragma unroll
    for (int j = 0; j < 4; ++j)
      acc[i][j] = (f32x4){0.f, 0.f, 0.f, 0.f};

  // stage one A region (256 rows x 32 k) = 2 x global_load_lds
  auto STAGE_A = [&](int base, int tile, int ks) {
    int k = tile * 64 + ks * 32;
    int kcol = k & 1023;
    int half = k >> 10;
    int sA0 = half ? sv0.y : sv0.x;
    int sA1 = half ? sv1.y : sv1.x;
    int dst = base + w * 512 + l * 8;
    __builtin_amdgcn_global_load_lds(
        (const AS1 void*)(hidBase + (((size_t)sA0) << 10) + kcol + gsrc * 8),
        (AS3 void*)&lds[dst], 16, 0, 0);
    __builtin_amdgcn_global_load_lds(
        (const AS1 void*)(hidBase + (((size_t)sA1) << 10) + kcol + gsrc * 8),
        (AS3 void*)&lds[dst + 4096], 16, 0, 0);
  };
  // stage one B region
  auto STAGE_B = [&](int base, int tile, int ks) {
    int k = tile * 64 + ks * 32;
    int dst = base + w * 512 + l * 8;
    __builtin_amdgcn_global_load_lds(
        (const AS1 void*)(w1t + (size_t)(n0 + r0) * K_ + k + gsrc * 8),
        (AS3 void*)&lds[dst], 16, 0, 0);
    __builtin_amdgcn_global_load_lds(
        (const AS1 void*)(w1t + (size_t)(n0 + r1) * K_ + k + gsrc * 8),
        (AS3 void*)&lds[dst + 4096], 16, 0, 0);
  };

#define VM6 asm volatile("s_waitcnt vmcnt(6)" ::: "memory")
#define VM4 asm volatile("s_waitcnt vmcnt(4)" ::: "memory")
#define VM0 asm volatile("s_waitcnt vmcnt(0)" ::: "memory")

  bf16x8 bv[4];   // B frags persist across the MH=0 -> MH=1 phase pair

// one sub-phase: {ds_read frags | stage one region | [vmcnt] | barrier |
//                 lgkmcnt(0) | 16 MFMA | barrier}
#define PHASE(SLOT, KS, MH, STAGEOP, WAITOP)                                   \
  {                                                                            \
    bf16x8 af[4];                                                              \
    _Pragma("unroll")                                                          \
    for (int mi = 0; mi < 4; ++mi)                                             \
      af[mi] = *(const bf16x8*)&lds[REG(SLOT, KS, 0) +                         \
          (wr * 128 + (MH) * 64 + mi * 16 + lr) * 32 + slot8];                 \
    if ((MH) == 0) {                                                           \
      _Pragma("unroll")                                                        \
      for (int ni = 0; ni < 4; ++ni)                                           \
        bv[ni] = *(const bf16x8*)&lds[REG(SLOT, KS, 1) +                       \
            (wn * 64 + ni * 16 + lr) * 32 + slot8];                            \
    }                                                                          \
    STAGEOP;                                                                   \
    WAITOP;                                                                    \
    __builtin_amdgcn_s_barrier();                                              \
    asm volatile("s_waitcnt lgkmcnt(0)" ::: "memory");                         \
    __builtin_amdgcn_sched_barrier(0);                                         \
    __builtin_amdgcn_s_setprio(1);                                             \
    _Pragma("unroll")                                                          \
    for (int mi = 0; mi < 4; ++mi)                                             \
      _Pragma("unroll")                                                        \
      for (int ni = 0; ni < 4; ++ni)                                           \
        acc[(MH) * 4 + mi][ni] = __builtin_amdgcn_mfma_f32_16x16x32_bf16(      \
            af[mi], bv[ni], acc[(MH) * 4 + mi][ni], 0, 0, 0);                  \
    __builtin_amdgcn_s_setprio(0);                                             \
    __builtin_amdgcn_s_barrier();                                              \
  }

  // ---- prologue: stage regions for phases 0..5 of iter 0 ----
  STAGE_A(REG(0, 0, 0), 0, 0); STAGE_B(REG(0, 0, 1), 0, 0);
  STAGE_A(REG(0, 1, 0), 0, 1); STAGE_B(REG(0, 1, 1), 0, 1);
  STAGE_A(REG(1, 0, 0), 1, 0); STAGE_B(REG(1, 0, 1), 1, 0);
  asm volatile("s_waitcnt vmcnt(8)" ::: "memory");   // tile0/ks0 A+B done
  __builtin_amdgcn_s_barrier();

  // ---- main loop: 15 full ring iterations (tiles 0..29 + stage 30,31) ----
  for (int u = 0; u < 15; ++u) {
    int t1 = 2 * u + 1, t2 = 2 * u + 2, t3 = 2 * u + 3;
    PHASE(0, 0, 0, STAGE_A(REG(1, 1, 0), t1, 1), VM6);
    PHASE(0, 0, 1, STAGE_B(REG(1, 1, 1), t1, 1), );
    PHASE(0, 1, 0, STAGE_A(REG(0, 0, 0), t2, 0), VM6);
    PHASE(0, 1, 1, STAGE_B(REG(0, 0, 1), t2, 0), );
    PHASE(1, 0, 0, STAGE_A(REG(0, 1, 0), t2, 1), VM6);
    PHASE(1, 0, 1, STAGE_B(REG(0, 1, 1), t2, 1), );
    PHASE(1, 1, 0, STAGE_A(REG(1, 0, 0), t3, 0), VM6);
    PHASE(1, 1, 1, STAGE_B(REG(1, 0, 1), t3, 0), );
  }
  // ---- epilogue iter (tiles 30, 31) ----
  PHASE(0, 0, 0, STAGE_A(REG(1, 1, 0), 31, 1), VM6);
  PHASE(0, 0, 1, STAGE_B(REG(1, 1, 1), 31, 1), );
  PHASE(0, 1, 0, , VM4);
  PHASE(0, 1, 1, , );
  PHASE(1, 0, 0, , VM0);
  PHASE(1, 0, 1, , );
  PHASE(1, 1, 0, , );
  PHASE(1, 1, 1, , );
#undef PHASE

  // ---- fused epilogue: bias + exact GELU + W2 contraction ----
  // acc element (mi,ni,j): row = wr*128+mi*16+lj*4+j, col = wn*64+ni*16+lr
  int q = nt * 4 + wn;
  float2* pOut = (float2*)part;
#pragma unroll
  for (int mi = 0; mi < 8; ++mi) {
    float s0[4] = {0.f, 0.f, 0.f, 0.f};
    float s1[4] = {0.f, 0.f, 0.f, 0.f};
#pragma unroll
    for (int ni = 0; ni < 4; ++ni) {
      int n = n0 + wn * 64 + ni * 16 + lr;
      float bb = b1[n];
      float2 wv = w2[n];
#pragma unroll
      for (int j = 0; j < 4; ++j) {
        float x = acc[mi][ni][j] + bb;
        float g = 0.5f * x * (1.0f + erff(x * 0.70710678118654752f));
        s0[j] += g * wv.x;
        s1[j] += g * wv.y;
      }
    }
#pragma unroll
    for (int off = 1; off < 16; off <<= 1) {
#pragma unroll
      for (int j = 0; j < 4; ++j) {
        s0[j] += __shfl_xor(s0[j], off, 64);
        s1[j] += __shfl_xor(s1[j], off, 64);
      }
    }
    if (lr == 0) {
#pragma unroll
      for (int j = 0; j < 4; ++j) {
        int m = m0 + wr * 128 + mi * 16 + lj * 4 + j;
        pOut[((size_t)q << 15) + m] = make_float2(s0[j], s1[j]);
      }
    }
  }
}

// ---- final reduce over 16 partials + b2 ---------------------------------
__global__ void reduce_k(const float2* __restrict__ part,
                         const float* __restrict__ b2,
                         float2* __restrict__ out) {
  int m = blockIdx.x * blockDim.x + threadIdx.x;
  if (m >= M_) return;
  float a0 = b2[0], a1 = b2[1];
#pragma unroll
  for (int q = 0; q < 16; ++q) {
    float2 v = part[((size_t)q << 15) + m];
    a0 += v.x; a1 += v.y;
  }
  out[m] = make_float2(a0, a1);
}

extern "C" void kernel_launch(void* const* d_in, const int* in_sizes, int n_in,
                              void* d_out, int out_size, void* d_ws, size_t ws_size,
                              hipStream_t stream) {
  const float* hidden = (const float*)d_in[0];
  const int*   pairs  = (const int*)d_in[1];
  const float* W1     = (const float*)d_in[2];
  const float* b1     = (const float*)d_in[3];
  const float* W2     = (const float*)d_in[4];
  const float* b2     = (const float*)d_in[5];
  float* out = (float*)d_out;

  // ws layout: hidden_bf16 (32 MiB) | W1T_bf16 (4 MiB) | partials (4 MiB)
  u16* hidB = (u16*)d_ws;
  u16* w1t  = hidB + (size_t)B_ * S_ * H_;
  float* part = (float*)(w1t + (size_t)H_ * K_);

  int n4 = (B_ * S_ * H_) / 4;
  cvt_hidden_k<<<4096, 256, 0, stream>>>((const float4*)hidden, (ushort4*)hidB, n4);
  transp_w1_k<<<dim3(H_ / 32, K_ / 32), dim3(32, 8), 0, stream>>>(W1, w1t);
  gemm_k<<<(M_ / 256) * (H_ / 256), 512, 0, stream>>>(
      hidB, w1t, pairs, b1, (const float2*)W2, part);
  reduce_k<<<(M_ + 255) / 256, 256, 0, stream>>>(
      (const float2*)part, b2, (float2*)out);
}